// Round 11
// baseline (144.115 us; speedup 1.0000x reference)
//
#include <hip/hip_runtime.h>
#include <math.h>

#define NPTS  16384
#define KNN   16
#define SEQV  8
#define NW    16      // waves per block
#define BATCH 8
#define CAPM  15      // append words/thread (flush thr -> max idx 14)
#define CAPR  1.001f  // radius cap in d2 space (d2>1 neighbors map to self)
#define NBKT  256
#define BSCALE 56.8888f   // NBKT / 4.5 norm range
#define HBLK  64      // hist/scatter blocks (256 pts each)
#define NGRP  256     // query groups of 64

// Transposed LDS slot: row t (0..15), column col (0..1023).
#define SLOT(arr, t, col) arr[(t) * 1024 + (col)]

// ws layout (bytes)
#define WS_HIST   256                         // NBKT*HBLK*4 = 64 KB
#define WS_STARTS 65792                       // 257*4
#define WS_SIDX   67072                       // (NPTS+8)*4
#define WS_SORTED 132640                      // (NPTS+8)*16, 16B aligned
#define WS_FLOWT  394912                      // SEQV*NPTS*16 = 2 MB, 16B aligned

__device__ __forceinline__ unsigned umin_(unsigned a, unsigned b) { return a < b ? a : b; }
__device__ __forceinline__ unsigned umax_(unsigned a, unsigned b) { return a > b ? a : b; }

// norm -> bucket, monotone; shared by scatter & window math (consistency!)
__device__ __forceinline__ int nbucket(float x) { return (int)fminf(x * BSCALE, 255.0f); }

// merge one key into sorted ascending keys[16] (scan-path flushes only)
// merge_one(0xFFFFFFFF) is a no-op -> sentinel padding is safe.
__device__ __forceinline__ void merge_one(unsigned keys[KNN], unsigned kk) {
    if (kk < keys[KNN - 1]) {
#pragma unroll
        for (int u = 0; u < KNN; ++u) {
            unsigned lo = umin_(kk, keys[u]);
            kk = umax_(kk, keys[u]);
            keys[u] = lo;
        }
    }
}

// Exact top-16 of two sorted-ascending 16-lists (bitonic, ~80 unpredicated ops)
__device__ __forceinline__ void merge16(unsigned k[KNN], const unsigned o[KNN]) {
    unsigned v[KNN];
#pragma unroll
    for (int i = 0; i < KNN; ++i) v[i] = umin_(k[i], o[KNN - 1 - i]);
#pragma unroll
    for (int d = 8; d >= 1; d >>= 1) {
#pragma unroll
        for (int i = 0; i < KNN; ++i) {
            if ((i & d) == 0) {
                unsigned lo = umin_(v[i], v[i + d]);
                unsigned hi = umax_(v[i], v[i + d]);
                v[i] = lo; v[i + d] = hi;
            }
        }
    }
#pragma unroll
    for (int i = 0; i < KNN; ++i) k[i] = v[i];
}

__device__ __forceinline__ void tree_load_merge(unsigned* uS, unsigned keys[KNN], int src) {
    unsigned o[KNN];
#pragma unroll
    for (int t = 0; t < KNN; ++t) o[t] = SLOT(uS, t, src);
    merge16(keys, o);
}

// ---------------------------------------------------------------------------
// K1: per-block LDS histogram -> hist[bin * HBLK + blk] + flow repack
// (flowT[s][i] = (fx,fy,fz,0) -> loss gathers one dwordx4/neighbor).
// 64 blocks x 256 threads (was 16 blocks -> 6% GPU; now 25%).
// ---------------------------------------------------------------------------
__global__ __launch_bounds__(256) void hist_kernel(
    const float* __restrict__ pc, const float* __restrict__ flow,
    unsigned* __restrict__ hist, float4* __restrict__ flowT)
{
    __shared__ unsigned h[NBKT];
    const int tid = threadIdx.x;
    h[tid] = 0u;
    __syncthreads();
    const int i = blockIdx.x * 256 + tid;
    const float x = pc[3 * i + 0], y = pc[3 * i + 1], z = pc[3 * i + 2];
    const float n = sqrtf(fmaf(x, x, fmaf(y, y, z * z)));
    atomicAdd(&h[nbucket(n)], 1u);
#pragma unroll
    for (int s = 0; s < SEQV; ++s) {
        const float* fp = flow + (size_t)s * NPTS * 3 + 3 * i;
        flowT[s * NPTS + i] = make_float4(fp[0], fp[1], fp[2], 0.0f);
    }
    __syncthreads();
    hist[tid * HBLK + blockIdx.x] = h[tid];
}

// ---------------------------------------------------------------------------
// K2: scatter into norm-bucketed order, PACKED form:
//   sorted4[pos] = (-2x, -2y, -2z, |c|^2)   -> scan d2p = 3 fma
//   sidx[pos]    = original index           -> keys keep orig-idx tie-break
// Each block redundantly computes the global prefix; block 0 publishes
// starts[] and zeroes accum. Sentinels at [NPTS, NPTS+8): d2p=1e18.
// ---------------------------------------------------------------------------
__global__ __launch_bounds__(256) void scatter_kernel(
    const float* __restrict__ pc, const unsigned* __restrict__ hist,
    unsigned* __restrict__ starts, float* __restrict__ accum,
    unsigned* __restrict__ sidx, float4* __restrict__ sorted4)
{
    __shared__ unsigned sH[NBKT];
    __shared__ unsigned sBase[NBKT];
    __shared__ unsigned sCnt[NBKT];
    const int tid = threadIdx.x;
    const int b   = blockIdx.x;

    unsigned own = 0, pre = 0;
    {
        const unsigned* row = hist + tid * HBLK;
        unsigned s = 0, p = 0;
#pragma unroll 8
        for (int k = 0; k < HBLK; ++k) {
            const unsigned c = row[k];
            if (k < b) p += c;
            s += c;
        }
        own = s; pre = p;
        sH[tid] = s;
        sCnt[tid] = 0u;
    }
    __syncthreads();
    for (int off = 1; off < NBKT; off <<= 1) {        // Hillis-Steele inclusive
        unsigned a = 0u;
        if (tid >= off) a = sH[tid - off];
        __syncthreads();
        sH[tid] += a;
        __syncthreads();
    }
    {
        const unsigned excl = sH[tid] - own;
        sBase[tid] = excl + pre;
        if (b == 0) starts[tid] = excl;
    }
    if (b == 0 && tid == 0) starts[NBKT] = NPTS;
    if (b == 0 && tid < 8) ((unsigned*)accum)[tid] = 0u;   // loss/wsum/ticket
    __syncthreads();

    const int i = b * 256 + tid;
    const float x = pc[3 * i + 0], y = pc[3 * i + 1], z = pc[3 * i + 2];
    const float c2 = fmaf(x, x, fmaf(y, y, z * z));
    const int bin = nbucket(sqrtf(c2));
    const unsigned rank = atomicAdd(&sCnt[bin], 1u);
    const unsigned pos = sBase[bin] + rank;
    sorted4[pos] = make_float4(-2.0f * x, -2.0f * y, -2.0f * z, c2);
    sidx[pos] = (unsigned)i;
    if (b == 0 && tid < 8) {
        sorted4[NPTS + tid] = make_float4(0.0f, 0.0f, 0.0f, 1e18f);
        sidx[NPTS + tid] = 0u;
    }
}

// ---------------------------------------------------------------------------
// K3: windowed mega — round-10 structure + CENTER-OUT Phase A with a
// DYNAMICALLY SHRINKING window. rA from the 1/4-sample tau is ~1.6x the
// ideal radius (E[sample-d16^2] ~ 2.5x true); scanning from the window
// midpoint outward (even waves ascend, odd descend, stride 8) tightens tau
// to ~true d16 early, and each wave periodically re-derives its own stop
// bound from the wave-max current tau -> the ~1.6x excess tail is provably
// skippable (norm-excluded => d2 > current tau >= margined keys[15] >=
// margined true-d16; order-independent). Tau-batch skip generalized to any
// wave (tau accepts live in the owner wave's seeded keys -> reach tree 2).
// Tau margin 8x -> 6x (cert-fail P ~ 1e-10).
// ---------------------------------------------------------------------------
__global__ __launch_bounds__(1024, 4) void mega_kernel(
    const float4* __restrict__ sorted, const unsigned* __restrict__ sidx,
    const unsigned* __restrict__ starts, const float4* __restrict__ flowT,
    const float* __restrict__ wts, float* __restrict__ accum,
    float* __restrict__ out)
{
    __shared__ unsigned uS[1024 * 16];   // 64 KB union: scan bufs / merge / ids
    float* sred = (float*)&uS[15 * 1024 + 1000];   // loss only
    float* sTau = (float*)&uS[16320];              // tree1-end .. Phase A
    // aux words 16316 (anyWide), 16317 (tauMax)

    const int tid  = threadIdx.x;
    const int lane = tid & 63;
    const int wv   = __builtin_amdgcn_readfirstlane(tid >> 6);   // 0..15
    const int is   = blockIdx.x * 64 + lane;       // sorted position

    const float4 mi = sorted[is];
    const float qx = -0.5f * mi.x;                 // exact (power-of-2)
    const float qy = -0.5f * mi.y;
    const float qz = -0.5f * mi.z;
    const float q2 = mi.w;
    const unsigned iorig = sidx[is];
    const float analytic = 0.14304f * exp2f(0.480898f * q2);   // 6x E[d16^2]
    const float tau0 = fminf(analytic, CAPR);

    const float nq = sqrtf(q2);
    float nmin = nq, nmax = nq;
#pragma unroll
    for (int off = 32; off > 0; off >>= 1) {
        nmin = fminf(nmin, __shfl_xor(nmin, off));
        nmax = fmaxf(nmax, __shfl_xor(nmax, off));
    }
    const float r0 = sqrtf(fminf(0.14304f * exp2f(0.480898f * nmax * nmax), CAPR));
    const int blo = nbucket(fmaxf(nmin - r0, 0.0f));
    const int bhi = nbucket(nmax + r0);
    const int kT0 = __builtin_amdgcn_readfirstlane((int)starts[blo]) >> 3;
    const int kTe = (__builtin_amdgcn_readfirstlane((int)starts[bhi + 1]) + 7) >> 3;

    unsigned keys[KNN];
#pragma unroll
    for (int t = 0; t < KNN; ++t) keys[t] = 0xFFFFFFFFu;
    int cnt = 0;
    unsigned* buf = &uS[tid * CAPM];               // stride 15 -> spread banks

    // ================= Tau phase: 1/4 sample, batches kT0+wv step 64 ======
    {
        float taufs = tau0 - q2;                   // d2p-space threshold
        float4 A[BATCH], Bv[BATCH];
        unsigned As[BATCH], Bs[BATCH];

        auto proc = [&](const float4* C, const unsigned* S) {
#pragma unroll
            for (int q = 0; q < BATCH; ++q) {
                const float4 c = C[q];
                float d2p = fmaf(c.x, qx, fmaf(c.y, qy, fmaf(c.z, qz, c.w)));
                bool acc = d2p <= taufs;
                if (__any(acc)) {                  // wave-rare branch
                    if (acc) {
                        float d2 = fmaxf(d2p + q2, 0.0f);
                        buf[cnt] = (__float_as_uint(d2) & 0xFFFFC000u) | S[q];
                        ++cnt;
                    }
                    if (__any(cnt >= CAPM - 1)) {  // COLLECTIVE flush
#pragma unroll 1
                        for (int t = 0; t < CAPM - 1; ++t)
                            merge_one(keys, (t < cnt) ? buf[t] : 0xFFFFFFFFu);
                        cnt = 0;
                        float d16n = __uint_as_float(keys[KNN - 1] & 0xFFFFC000u);
                        taufs = fminf(taufs, fmaf(d16n, 1.0002f, 1e-6f) - q2);
                    }
                }
            }
        };

        int k = kT0 + wv;
        bool hA = (k < kTe);
        if (hA) { const float4* bp = sorted + (k << 3); const unsigned* sp = sidx + (k << 3);
#pragma unroll
            for (int q = 0; q < BATCH; ++q) { A[q] = bp[q]; As[q] = sp[q]; } }
        while (hA) {
            int k2 = k + 64; bool hB = (k2 < kTe);
            if (hB) { const float4* bp = sorted + (k2 << 3); const unsigned* sp = sidx + (k2 << 3);
#pragma unroll
                for (int q = 0; q < BATCH; ++q) { Bv[q] = bp[q]; Bs[q] = sp[q]; } }
            proc(A, As);
            if (!hB) break;
            int k3 = k2 + 64; bool hC = (k3 < kTe);
            if (hC) { const float4* bp = sorted + (k3 << 3); const unsigned* sp = sidx + (k3 << 3);
#pragma unroll
                for (int q = 0; q < BATCH; ++q) { A[q] = bp[q]; As[q] = sp[q]; } }
            proc(Bv, Bs);
            k = k3; hA = hC;
        }
#pragma unroll 1
        for (int t = 0; t < CAPM - 1; ++t)         // collective drain
            merge_one(keys, (t < cnt) ? buf[t] : 0xFFFFFFFFu);
        cnt = 0;
    }

    // save tau keys across tree merge 1 (registers; Phase A seeds from them)
    unsigned keys2[KNN];
#pragma unroll
    for (int t = 0; t < KNN; ++t) keys2[t] = keys[t];

    __syncthreads();   // bufs dead; reuse uS as transposed merge slots

    // ================= Tree merge 1 -> sample tau + cert ==================
#pragma unroll
    for (int t = 0; t < KNN; ++t) SLOT(uS, t, tid) = keys[t];
    __syncthreads();
    if (wv < 8) {
        tree_load_merge(uS, keys, tid + 512);
#pragma unroll
        for (int t = 0; t < KNN; ++t) SLOT(uS, t, tid) = keys[t];
    }
    __syncthreads();
    if (wv < 4) {
        tree_load_merge(uS, keys, tid + 256);
#pragma unroll
        for (int t = 0; t < KNN; ++t) SLOT(uS, t, tid) = keys[t];
    }
    __syncthreads();
    if (wv < 2) {
        tree_load_merge(uS, keys, tid + 128);
#pragma unroll
        for (int t = 0; t < KNN; ++t) SLOT(uS, t, tid) = keys[t];
    }
    __syncthreads();
    if (wv == 0) {
        tree_load_merge(uS, keys, tid + 64);
        const float d16 = __uint_as_float(keys[KNN - 1] & 0xFFFFC000u);
        const float tf  = fmaf(d16, 1.0002f, 1e-6f);
        const bool fail = !(tf <= tau0);           // NaN sentinel -> fail
        const float tv = fail ? CAPR : tf;
        sTau[lane] = tv;
        float tm = tv;
#pragma unroll
        for (int off = 32; off > 0; off >>= 1) tm = fmaxf(tm, __shfl_xor(tm, off));
        unsigned long long bw = __ballot(fail && (analytic < CAPR));
        if (lane == 0) { uS[16316] = (bw != 0ull) ? 1u : 0u; ((float*)uS)[16317] = tm; }
    }
    __syncthreads();

    // ================= Phase A: center-out, dynamic window ================
    float taufs = sTau[lane] - q2;
    const unsigned anyWide = __builtin_amdgcn_readfirstlane(uS[16316]);
    const float rA = sqrtf(((float*)uS)[16317]);
    int kA0, kAe;
    if (anyWide) { kA0 = 0; kAe = NPTS / 8; }
    else {
        int bloA = nbucket(fmaxf(nmin - rA, 0.0f));
        int bhiA = nbucket(nmax + rA);
        kA0 = __builtin_amdgcn_readfirstlane((int)starts[bloA]) >> 3;
        kAe = (__builtin_amdgcn_readfirstlane((int)starts[bhiA + 1]) + 7) >> 3;
    }
#pragma unroll
    for (int t = 0; t < KNN; ++t) keys[t] = keys2[t];   // seed with tau keys
    {
        float4 A[BATCH], Bv[BATCH];
        unsigned As[BATCH], Bs[BATCH];

        auto proc = [&](const float4* C, const unsigned* S) {
#pragma unroll
            for (int q = 0; q < BATCH; ++q) {
                const float4 c = C[q];
                float d2p = fmaf(c.x, qx, fmaf(c.y, qy, fmaf(c.z, qz, c.w)));
                bool acc = d2p <= taufs;
                if (__any(acc)) {                  // wave-rare branch
                    if (acc) {
                        float d2 = fmaxf(d2p + q2, 0.0f);
                        buf[cnt] = (__float_as_uint(d2) & 0xFFFFC000u) | S[q];
                        ++cnt;
                    }
                    if (__any(cnt >= CAPM - 1)) {  // COLLECTIVE flush
#pragma unroll 1
                        for (int t = 0; t < CAPM - 1; ++t)
                            merge_one(keys, (t < cnt) ? buf[t] : 0xFFFFFFFFu);
                        cnt = 0;
                        float d16n = __uint_as_float(keys[KNN - 1] & 0xFFFFC000u);
                        taufs = fminf(taufs, fmaf(d16n, 1.0002f, 1e-6f) - q2);
                    }
                }
            }
        };

        const int dir = (wv & 1) ? -8 : 8;         // even up, odd down
        const int c0  = kA0 + ((kAe - kA0) >> 1);
        int kLo = kA0, kHi = kAe;                  // dynamic bounds
        // tau-scanned batches (residue 0..15 mod 64 in tau window): any wave
        // may skip them — tau accepts live in owner wave's seeded keys.
        auto skipb = [&](int k) -> bool {
            return (!anyWide) && (k >= kT0) && (k < kTe)
                && (((k - kT0) & 63) < 16);
        };
        auto advk = [&](int k) { do { k += dir; } while (skipb(k)); return k; };
        auto inb  = [&](int k) { return (dir > 0) ? (k < kHi) : (k >= kLo); };

        int k = (dir > 0) ? (c0 + (wv >> 1)) : (c0 - 1 - (wv >> 1));
        while (skipb(k)) k += dir;
        int iter = 0;
        bool hA = inb(k);
        if (hA) { const float4* bp = sorted + (k << 3); const unsigned* sp = sidx + (k << 3);
#pragma unroll
            for (int q = 0; q < BATCH; ++q) { A[q] = bp[q]; As[q] = sp[q]; } }
        while (hA) {
            int k2 = advk(k);
            if (((++iter) & 3) == 0) {             // re-tighten own bound
                float td = taufs + q2;
#pragma unroll
                for (int off = 32; off > 0; off >>= 1)
                    td = fmaxf(td, __shfl_xor(td, off));
                float rr = sqrtf(td);
                if (dir > 0) {
                    int bh = nbucket(nmax + rr);
                    int ne = (__builtin_amdgcn_readfirstlane((int)starts[bh + 1]) + 7) >> 3;
                    kHi = (ne < kHi) ? ne : kHi;
                } else {
                    int bl = nbucket(fmaxf(nmin - rr, 0.0f));
                    int ns = __builtin_amdgcn_readfirstlane((int)starts[bl]) >> 3;
                    kLo = (ns > kLo) ? ns : kLo;
                }
            }
            bool hB = inb(k2);
            if (hB) { const float4* bp = sorted + (k2 << 3); const unsigned* sp = sidx + (k2 << 3);
#pragma unroll
                for (int q = 0; q < BATCH; ++q) { Bv[q] = bp[q]; Bs[q] = sp[q]; } }
            proc(A, As);
            if (!hB) break;
            int k3 = advk(k2);
            bool hC = inb(k3);
            if (hC) { const float4* bp = sorted + (k3 << 3); const unsigned* sp = sidx + (k3 << 3);
#pragma unroll
                for (int q = 0; q < BATCH; ++q) { A[q] = bp[q]; As[q] = sp[q]; } }
            proc(Bv, Bs);
            k = k3; hA = hC;
        }
#pragma unroll 1
        for (int t = 0; t < CAPM - 1; ++t)         // collective drain
            merge_one(keys, (t < cnt) ? buf[t] : 0xFFFFFFFFu);
    }
    __syncthreads();   // scan buffers dead; reuse uS for tree 2

    // ================= Tree merge 2 -> radius -> ids (orig) ===============
#pragma unroll
    for (int t = 0; t < KNN; ++t) SLOT(uS, t, tid) = keys[t];
    __syncthreads();
    if (wv < 8) {
        tree_load_merge(uS, keys, tid + 512);
#pragma unroll
        for (int t = 0; t < KNN; ++t) SLOT(uS, t, tid) = keys[t];
    }
    __syncthreads();
    if (wv < 4) {
        tree_load_merge(uS, keys, tid + 256);
#pragma unroll
        for (int t = 0; t < KNN; ++t) SLOT(uS, t, tid) = keys[t];
    }
    __syncthreads();
    if (wv < 2) {
        tree_load_merge(uS, keys, tid + 128);
#pragma unroll
        for (int t = 0; t < KNN; ++t) SLOT(uS, t, tid) = keys[t];
    }
    __syncthreads();
    if (wv == 0) {
        tree_load_merge(uS, keys, tid + 64);
        const int id0 = (int)(keys[0] & 0x3FFFu);   // nearest (self, orig idx)
#pragma unroll
        for (int t = 0; t < KNN; ++t) {
            float d2t = __uint_as_float(keys[t] & 0xFFFFC000u);
            int   j   = (int)(keys[t] & 0x3FFFu);
            SLOT(uS, t, lane) = (unsigned)((d2t > 1.0f) ? id0 : j);
        }
    }
    __syncthreads();

    // ================= Loss + reduce + finalize ===========================
    {
        const int s  = wv & 7;
        const int kh = wv >> 3;
        const float4* fs4 = flowT + (size_t)s * NPTS;
        const float4 qf = fs4[iorig];

        float sum = 0.0f;
#pragma unroll
        for (int z = 0; z < 8; ++z) {
            int j = (int)SLOT(uS, kh * 8 + z, lane);   // conflict-free
            const float4 v = fs4[j];                   // one dwordx4 gather
            float dx = qf.x - v.x;
            float dy = qf.y - v.y;
            float dz = qf.z - v.z;
            float sq = fmaf(dx, dx, fmaf(dy, dy, dz * dz));
            sum += (sq > 0.0f) ? sqrtf(sq) : 0.0f;
        }

        float contrib = wts[iorig] * sum;
#pragma unroll
        for (int off = 32; off > 0; off >>= 1) contrib += __shfl_down(contrib, off);
        if (lane == 0) sred[wv] = contrib;

        if (wv == 0) {                       // weight sum, once per block
            float wi = wts[iorig];
#pragma unroll
            for (int off = 32; off > 0; off >>= 1) wi += __shfl_down(wi, off);
            if (lane == 0) atomicAdd(&accum[1], wi);
        }
        __syncthreads();

        if (tid == 0) {
            float c = 0.0f;
#pragma unroll
            for (int t = 0; t < NW; ++t) c += sred[t];
            atomicAdd(&accum[0], c);
            __threadfence();
            unsigned ticket = atomicAdd((unsigned*)accum + 2, 1u);
            if (ticket == gridDim.x - 1) {   // last block finalizes
                float a  = atomicAdd(&accum[0], 0.0f);   // coherent read
                float ws = atomicAdd(&accum[1], 0.0f);
                float v  = a / (float)(KNN * SEQV);
                out[0] = (ws > 0.0f) ? (v / ws) : v;
            }
        }
    }
}

extern "C" void kernel_launch(void* const* d_in, const int* in_sizes, int n_in,
                              void* d_out, int out_size, void* d_ws, size_t ws_size,
                              hipStream_t stream)
{
    const float* pc   = (const float*)d_in[0];   // (1, N, 3)
    const float* flow = (const float*)d_in[1];   // (SEQ, N, 3)
    const float* wts  = (const float*)d_in[2];   // (N,)
    float* out = (float*)d_out;

    float*    accum  = (float*)d_ws;
    unsigned* hist   = (unsigned*)((char*)d_ws + WS_HIST);
    unsigned* starts = (unsigned*)((char*)d_ws + WS_STARTS);
    unsigned* sidx   = (unsigned*)((char*)d_ws + WS_SIDX);
    float4*   sorted = (float4*)  ((char*)d_ws + WS_SORTED);
    float4*   flowT  = (float4*)  ((char*)d_ws + WS_FLOWT);

    hist_kernel   <<<HBLK, 256, 0, stream>>>(pc, flow, hist, flowT);
    scatter_kernel<<<HBLK, 256, 0, stream>>>(pc, hist, starts, accum, sidx, sorted);
    mega_kernel   <<<NGRP, 1024, 0, stream>>>(sorted, sidx, starts, flowT, wts, accum, out);
}

// Round 12
// 130.851 us; speedup vs baseline: 1.1014x; 1.1014x over previous
//
#include <hip/hip_runtime.h>
#include <math.h>

#define NPTS  16384
#define KNN   16
#define SEQV  8
#define NW    16      // waves per block
#define BATCH 8
#define CAPM  15      // append words/thread (flush thr -> max idx 14)
#define CAPR  1.001f  // radius cap in d2 space (d2>1 neighbors map to self)
#define NBKT  256
#define BSCALE 56.8888f   // NBKT / 4.5 norm range
#define HBLK  64      // hist/scatter blocks (256 pts each)
#define NGRP  256     // query groups of 64

// Transposed LDS slot: row t (0..15), column col (0..1023).
#define SLOT(arr, t, col) arr[(t) * 1024 + (col)]

// ws layout (bytes)
#define WS_HIST   256                         // NBKT*HBLK*4 = 64 KB
#define WS_STARTS 65792                       // 257*4
#define WS_SIDX   67072                       // (NPTS+8)*4
#define WS_SORTED 132640                      // (NPTS+8)*16, 16B aligned
#define WS_FLOWT  394912                      // SEQV*NPTS*16 = 2 MB, 16B aligned

__device__ __forceinline__ unsigned umin_(unsigned a, unsigned b) { return a < b ? a : b; }
__device__ __forceinline__ unsigned umax_(unsigned a, unsigned b) { return a > b ? a : b; }

// norm -> bucket, monotone; shared by scatter & window math (consistency!)
__device__ __forceinline__ int nbucket(float x) { return (int)fminf(x * BSCALE, 255.0f); }

// merge one key into sorted ascending keys[16] (scan-path flushes only)
// merge_one(0xFFFFFFFF) is a no-op -> sentinel padding is safe.
__device__ __forceinline__ void merge_one(unsigned keys[KNN], unsigned kk) {
    if (kk < keys[KNN - 1]) {
#pragma unroll
        for (int u = 0; u < KNN; ++u) {
            unsigned lo = umin_(kk, keys[u]);
            kk = umax_(kk, keys[u]);
            keys[u] = lo;
        }
    }
}

// Exact top-16 of two sorted-ascending 16-lists (bitonic, ~80 unpredicated ops)
__device__ __forceinline__ void merge16(unsigned k[KNN], const unsigned o[KNN]) {
    unsigned v[KNN];
#pragma unroll
    for (int i = 0; i < KNN; ++i) v[i] = umin_(k[i], o[KNN - 1 - i]);
#pragma unroll
    for (int d = 8; d >= 1; d >>= 1) {
#pragma unroll
        for (int i = 0; i < KNN; ++i) {
            if ((i & d) == 0) {
                unsigned lo = umin_(v[i], v[i + d]);
                unsigned hi = umax_(v[i], v[i + d]);
                v[i] = lo; v[i + d] = hi;
            }
        }
    }
#pragma unroll
    for (int i = 0; i < KNN; ++i) k[i] = v[i];
}

__device__ __forceinline__ void tree_load_merge(unsigned* uS, unsigned keys[KNN], int src) {
    unsigned o[KNN];
#pragma unroll
    for (int t = 0; t < KNN; ++t) o[t] = SLOT(uS, t, src);
    merge16(keys, o);
}

// ---------------------------------------------------------------------------
// K1: per-block LDS histogram -> hist[bin * HBLK + blk] + flow repack
// (flowT[s][i] = (fx,fy,fz,0) -> loss gathers one dwordx4/neighbor).
// 64 blocks x 256 threads.
// ---------------------------------------------------------------------------
__global__ __launch_bounds__(256) void hist_kernel(
    const float* __restrict__ pc, const float* __restrict__ flow,
    unsigned* __restrict__ hist, float4* __restrict__ flowT)
{
    __shared__ unsigned h[NBKT];
    const int tid = threadIdx.x;
    h[tid] = 0u;
    __syncthreads();
    const int i = blockIdx.x * 256 + tid;
    const float x = pc[3 * i + 0], y = pc[3 * i + 1], z = pc[3 * i + 2];
    const float n = sqrtf(fmaf(x, x, fmaf(y, y, z * z)));
    atomicAdd(&h[nbucket(n)], 1u);
#pragma unroll
    for (int s = 0; s < SEQV; ++s) {
        const float* fp = flow + (size_t)s * NPTS * 3 + 3 * i;
        flowT[s * NPTS + i] = make_float4(fp[0], fp[1], fp[2], 0.0f);
    }
    __syncthreads();
    hist[tid * HBLK + blockIdx.x] = h[tid];
}

// ---------------------------------------------------------------------------
// K2: scatter into norm-bucketed order, PACKED form:
//   sorted4[pos] = (-2x, -2y, -2z, |c|^2)   -> scan d2p = 3 fma
//   sidx[pos]    = original index           -> keys keep orig-idx tie-break
// Each block redundantly computes the global prefix; block 0 publishes
// starts[] and zeroes accum. Sentinels at [NPTS, NPTS+8): d2p=1e18.
// ---------------------------------------------------------------------------
__global__ __launch_bounds__(256) void scatter_kernel(
    const float* __restrict__ pc, const unsigned* __restrict__ hist,
    unsigned* __restrict__ starts, float* __restrict__ accum,
    unsigned* __restrict__ sidx, float4* __restrict__ sorted4)
{
    __shared__ unsigned sH[NBKT];
    __shared__ unsigned sBase[NBKT];
    __shared__ unsigned sCnt[NBKT];
    const int tid = threadIdx.x;
    const int b   = blockIdx.x;

    unsigned own = 0, pre = 0;
    {
        const unsigned* row = hist + tid * HBLK;
        unsigned s = 0, p = 0;
#pragma unroll 8
        for (int k = 0; k < HBLK; ++k) {
            const unsigned c = row[k];
            if (k < b) p += c;
            s += c;
        }
        own = s; pre = p;
        sH[tid] = s;
        sCnt[tid] = 0u;
    }
    __syncthreads();
    for (int off = 1; off < NBKT; off <<= 1) {        // Hillis-Steele inclusive
        unsigned a = 0u;
        if (tid >= off) a = sH[tid - off];
        __syncthreads();
        sH[tid] += a;
        __syncthreads();
    }
    {
        const unsigned excl = sH[tid] - own;
        sBase[tid] = excl + pre;
        if (b == 0) starts[tid] = excl;
    }
    if (b == 0 && tid == 0) starts[NBKT] = NPTS;
    if (b == 0 && tid < 8) ((unsigned*)accum)[tid] = 0u;   // loss/wsum/ticket
    __syncthreads();

    const int i = b * 256 + tid;
    const float x = pc[3 * i + 0], y = pc[3 * i + 1], z = pc[3 * i + 2];
    const float c2 = fmaf(x, x, fmaf(y, y, z * z));
    const int bin = nbucket(sqrtf(c2));
    const unsigned rank = atomicAdd(&sCnt[bin], 1u);
    const unsigned pos = sBase[bin] + rank;
    sorted4[pos] = make_float4(-2.0f * x, -2.0f * y, -2.0f * z, c2);
    sidx[pos] = (unsigned)i;
    if (b == 0 && tid < 8) {
        sorted4[NPTS + tid] = make_float4(0.0f, 0.0f, 0.0f, 1e18f);
        sidx[NPTS + tid] = 0u;
    }
}

// ---------------------------------------------------------------------------
// K3: windowed mega — ROUND-10 form verbatim (proven 71.4us: strided Phase A
// with owner-aligned tau-batch skip, collective flushes, flowT gathers).
// Round-11's center-out dynamic window REGRESSED (85.8us: per-batch skip/
// bounds overhead without actual window shrink — FETCH unchanged) and is
// reverted. Only retained co-riders: 6x analytic margin (tau window -13%,
// cert-fail P ~ 1e-15, CAPR fallback correct) and HBLK=64 pre-kernels.
// ---------------------------------------------------------------------------
__global__ __launch_bounds__(1024, 4) void mega_kernel(
    const float4* __restrict__ sorted, const unsigned* __restrict__ sidx,
    const unsigned* __restrict__ starts, const float4* __restrict__ flowT,
    const float* __restrict__ wts, float* __restrict__ accum,
    float* __restrict__ out)
{
    __shared__ unsigned uS[1024 * 16];   // 64 KB union: scan bufs / merge / ids
    float* sred = (float*)&uS[15 * 1024 + 1000];   // loss only
    float* sTau = (float*)&uS[16320];              // tree1-end .. Phase A
    // aux words 16316 (anyWide), 16317 (tauMax)

    const int tid  = threadIdx.x;
    const int lane = tid & 63;
    const int wv   = __builtin_amdgcn_readfirstlane(tid >> 6);   // 0..15
    const int is   = blockIdx.x * 64 + lane;       // sorted position

    const float4 mi = sorted[is];
    const float qx = -0.5f * mi.x;                 // exact (power-of-2)
    const float qy = -0.5f * mi.y;
    const float qz = -0.5f * mi.z;
    const float q2 = mi.w;
    const unsigned iorig = sidx[is];
    const float analytic = 0.14304f * exp2f(0.480898f * q2);   // 6x E[d16^2]
    const float tau0 = fminf(analytic, CAPR);

    const float nq = sqrtf(q2);
    float nmin = nq, nmax = nq;
#pragma unroll
    for (int off = 32; off > 0; off >>= 1) {
        nmin = fminf(nmin, __shfl_xor(nmin, off));
        nmax = fmaxf(nmax, __shfl_xor(nmax, off));
    }
    const float r0 = sqrtf(fminf(0.14304f * exp2f(0.480898f * nmax * nmax), CAPR));
    const int blo = nbucket(fmaxf(nmin - r0, 0.0f));
    const int bhi = nbucket(nmax + r0);
    const int kT0 = __builtin_amdgcn_readfirstlane((int)starts[blo]) >> 3;
    const int kTe = (__builtin_amdgcn_readfirstlane((int)starts[bhi + 1]) + 7) >> 3;

    unsigned keys[KNN];
#pragma unroll
    for (int t = 0; t < KNN; ++t) keys[t] = 0xFFFFFFFFu;
    int cnt = 0;
    unsigned* buf = &uS[tid * CAPM];               // stride 15 -> spread banks

    // ================= Tau phase: 1/4 sample, batches kT0+wv step 64 ======
    {
        float taufs = tau0 - q2;                   // d2p-space threshold
        float4 A[BATCH], Bv[BATCH];
        unsigned As[BATCH], Bs[BATCH];

        auto proc = [&](const float4* C, const unsigned* S) {
#pragma unroll
            for (int q = 0; q < BATCH; ++q) {
                const float4 c = C[q];
                float d2p = fmaf(c.x, qx, fmaf(c.y, qy, fmaf(c.z, qz, c.w)));
                bool acc = d2p <= taufs;
                if (__any(acc)) {                  // wave-rare branch
                    if (acc) {
                        float d2 = fmaxf(d2p + q2, 0.0f);
                        buf[cnt] = (__float_as_uint(d2) & 0xFFFFC000u) | S[q];
                        ++cnt;
                    }
                    if (__any(cnt >= CAPM - 1)) {  // COLLECTIVE flush
#pragma unroll 1
                        for (int t = 0; t < CAPM - 1; ++t)
                            merge_one(keys, (t < cnt) ? buf[t] : 0xFFFFFFFFu);
                        cnt = 0;
                        float d16n = __uint_as_float(keys[KNN - 1] & 0xFFFFC000u);
                        taufs = fminf(taufs, fmaf(d16n, 1.0002f, 1e-6f) - q2);
                    }
                }
            }
        };

        int k = kT0 + wv;
        bool hA = (k < kTe);
        if (hA) { const float4* bp = sorted + (k << 3); const unsigned* sp = sidx + (k << 3);
#pragma unroll
            for (int q = 0; q < BATCH; ++q) { A[q] = bp[q]; As[q] = sp[q]; } }
        while (hA) {
            int k2 = k + 64; bool hB = (k2 < kTe);
            if (hB) { const float4* bp = sorted + (k2 << 3); const unsigned* sp = sidx + (k2 << 3);
#pragma unroll
                for (int q = 0; q < BATCH; ++q) { Bv[q] = bp[q]; Bs[q] = sp[q]; } }
            proc(A, As);
            if (!hB) break;
            int k3 = k2 + 64; bool hC = (k3 < kTe);
            if (hC) { const float4* bp = sorted + (k3 << 3); const unsigned* sp = sidx + (k3 << 3);
#pragma unroll
                for (int q = 0; q < BATCH; ++q) { A[q] = bp[q]; As[q] = sp[q]; } }
            proc(Bv, Bs);
            k = k3; hA = hC;
        }
#pragma unroll 1
        for (int t = 0; t < CAPM - 1; ++t)         // collective drain
            merge_one(keys, (t < cnt) ? buf[t] : 0xFFFFFFFFu);
        cnt = 0;
    }

    // save tau keys across tree merge 1 (registers; Phase A seeds from them)
    unsigned keys2[KNN];
#pragma unroll
    for (int t = 0; t < KNN; ++t) keys2[t] = keys[t];

    __syncthreads();   // bufs dead; reuse uS as transposed merge slots

    // ================= Tree merge 1 -> sample tau + cert ==================
#pragma unroll
    for (int t = 0; t < KNN; ++t) SLOT(uS, t, tid) = keys[t];
    __syncthreads();
    if (wv < 8) {
        tree_load_merge(uS, keys, tid + 512);
#pragma unroll
        for (int t = 0; t < KNN; ++t) SLOT(uS, t, tid) = keys[t];
    }
    __syncthreads();
    if (wv < 4) {
        tree_load_merge(uS, keys, tid + 256);
#pragma unroll
        for (int t = 0; t < KNN; ++t) SLOT(uS, t, tid) = keys[t];
    }
    __syncthreads();
    if (wv < 2) {
        tree_load_merge(uS, keys, tid + 128);
#pragma unroll
        for (int t = 0; t < KNN; ++t) SLOT(uS, t, tid) = keys[t];
    }
    __syncthreads();
    if (wv == 0) {
        tree_load_merge(uS, keys, tid + 64);
        const float d16 = __uint_as_float(keys[KNN - 1] & 0xFFFFC000u);
        const float tf  = fmaf(d16, 1.0002f, 1e-6f);
        const bool fail = !(tf <= tau0);           // NaN sentinel -> fail
        const float tv = fail ? CAPR : tf;
        sTau[lane] = tv;
        float tm = tv;
#pragma unroll
        for (int off = 32; off > 0; off >>= 1) tm = fmaxf(tm, __shfl_xor(tm, off));
        unsigned long long bw = __ballot(fail && (analytic < CAPR));
        if (lane == 0) { uS[16316] = (bw != 0ull) ? 1u : 0u; ((float*)uS)[16317] = tm; }
    }
    __syncthreads();

    // ================= Phase A: tight window, skip own tau batches ========
    float taufs = sTau[lane] - q2;
    const unsigned anyWide = __builtin_amdgcn_readfirstlane(uS[16316]);
    const float rA = sqrtf(((float*)uS)[16317]);
    int kA0, kAe;
    if (anyWide) { kA0 = 0; kAe = NPTS / 8; }
    else {
        int bloA = nbucket(fmaxf(nmin - rA, 0.0f));
        int bhiA = nbucket(nmax + rA);
        kA0 = __builtin_amdgcn_readfirstlane((int)starts[bloA]) >> 3;
        kAe = (__builtin_amdgcn_readfirstlane((int)starts[bhiA + 1]) + 7) >> 3;
    }
#pragma unroll
    for (int t = 0; t < KNN; ++t) keys[t] = keys2[t];   // seed with tau keys
    {
        float4 A[BATCH], Bv[BATCH];
        unsigned As[BATCH], Bs[BATCH];

        auto proc = [&](const float4* C, const unsigned* S) {
#pragma unroll
            for (int q = 0; q < BATCH; ++q) {
                const float4 c = C[q];
                float d2p = fmaf(c.x, qx, fmaf(c.y, qy, fmaf(c.z, qz, c.w)));
                bool acc = d2p <= taufs;
                if (__any(acc)) {                  // wave-rare branch
                    if (acc) {
                        float d2 = fmaxf(d2p + q2, 0.0f);
                        buf[cnt] = (__float_as_uint(d2) & 0xFFFFC000u) | S[q];
                        ++cnt;
                    }
                    if (__any(cnt >= CAPM - 1)) {  // COLLECTIVE flush
#pragma unroll 1
                        for (int t = 0; t < CAPM - 1; ++t)
                            merge_one(keys, (t < cnt) ? buf[t] : 0xFFFFFFFFu);
                        cnt = 0;
                        float d16n = __uint_as_float(keys[KNN - 1] & 0xFFFFC000u);
                        taufs = fminf(taufs, fmaf(d16n, 1.0002f, 1e-6f) - q2);
                    }
                }
            }
        };

        // wave assignment aligned to kT0 so tau batches land on their owner
        auto skipb = [&](int k) -> bool {
            return (!anyWide) && (k < kTe) && (((k - kT0 - wv) & 63) == 0);
        };
        int k = kA0 + ((wv - (kA0 - kT0)) & 15);
        if (skipb(k)) k += 16;                     // skips never consecutive
        bool hA = (k < kAe);
        if (hA) { const float4* bp = sorted + (k << 3); const unsigned* sp = sidx + (k << 3);
#pragma unroll
            for (int q = 0; q < BATCH; ++q) { A[q] = bp[q]; As[q] = sp[q]; } }
        while (hA) {
            int k2 = k + 16; if (skipb(k2)) k2 += 16;
            bool hB = (k2 < kAe);
            if (hB) { const float4* bp = sorted + (k2 << 3); const unsigned* sp = sidx + (k2 << 3);
#pragma unroll
                for (int q = 0; q < BATCH; ++q) { Bv[q] = bp[q]; Bs[q] = sp[q]; } }
            proc(A, As);
            if (!hB) break;
            int k3 = k2 + 16; if (skipb(k3)) k3 += 16;
            bool hC = (k3 < kAe);
            if (hC) { const float4* bp = sorted + (k3 << 3); const unsigned* sp = sidx + (k3 << 3);
#pragma unroll
                for (int q = 0; q < BATCH; ++q) { A[q] = bp[q]; As[q] = sp[q]; } }
            proc(Bv, Bs);
            k = k3; hA = hC;
        }
#pragma unroll 1
        for (int t = 0; t < CAPM - 1; ++t)         // collective drain
            merge_one(keys, (t < cnt) ? buf[t] : 0xFFFFFFFFu);
    }
    __syncthreads();   // scan buffers dead; reuse uS for tree 2

    // ================= Tree merge 2 -> radius -> ids (orig) ===============
#pragma unroll
    for (int t = 0; t < KNN; ++t) SLOT(uS, t, tid) = keys[t];
    __syncthreads();
    if (wv < 8) {
        tree_load_merge(uS, keys, tid + 512);
#pragma unroll
        for (int t = 0; t < KNN; ++t) SLOT(uS, t, tid) = keys[t];
    }
    __syncthreads();
    if (wv < 4) {
        tree_load_merge(uS, keys, tid + 256);
#pragma unroll
        for (int t = 0; t < KNN; ++t) SLOT(uS, t, tid) = keys[t];
    }
    __syncthreads();
    if (wv < 2) {
        tree_load_merge(uS, keys, tid + 128);
#pragma unroll
        for (int t = 0; t < KNN; ++t) SLOT(uS, t, tid) = keys[t];
    }
    __syncthreads();
    if (wv == 0) {
        tree_load_merge(uS, keys, tid + 64);
        const int id0 = (int)(keys[0] & 0x3FFFu);   // nearest (self, orig idx)
#pragma unroll
        for (int t = 0; t < KNN; ++t) {
            float d2t = __uint_as_float(keys[t] & 0xFFFFC000u);
            int   j   = (int)(keys[t] & 0x3FFFu);
            SLOT(uS, t, lane) = (unsigned)((d2t > 1.0f) ? id0 : j);
        }
    }
    __syncthreads();

    // ================= Loss + reduce + finalize ===========================
    {
        const int s  = wv & 7;
        const int kh = wv >> 3;
        const float4* fs4 = flowT + (size_t)s * NPTS;
        const float4 qf = fs4[iorig];

        float sum = 0.0f;
#pragma unroll
        for (int z = 0; z < 8; ++z) {
            int j = (int)SLOT(uS, kh * 8 + z, lane);   // conflict-free
            const float4 v = fs4[j];                   // one dwordx4 gather
            float dx = qf.x - v.x;
            float dy = qf.y - v.y;
            float dz = qf.z - v.z;
            float sq = fmaf(dx, dx, fmaf(dy, dy, dz * dz));
            sum += (sq > 0.0f) ? sqrtf(sq) : 0.0f;
        }

        float contrib = wts[iorig] * sum;
#pragma unroll
        for (int off = 32; off > 0; off >>= 1) contrib += __shfl_down(contrib, off);
        if (lane == 0) sred[wv] = contrib;

        if (wv == 0) {                       // weight sum, once per block
            float wi = wts[iorig];
#pragma unroll
            for (int off = 32; off > 0; off >>= 1) wi += __shfl_down(wi, off);
            if (lane == 0) atomicAdd(&accum[1], wi);
        }
        __syncthreads();

        if (tid == 0) {
            float c = 0.0f;
#pragma unroll
            for (int t = 0; t < NW; ++t) c += sred[t];
            atomicAdd(&accum[0], c);
            __threadfence();
            unsigned ticket = atomicAdd((unsigned*)accum + 2, 1u);
            if (ticket == gridDim.x - 1) {   // last block finalizes
                float a  = atomicAdd(&accum[0], 0.0f);   // coherent read
                float ws = atomicAdd(&accum[1], 0.0f);
                float v  = a / (float)(KNN * SEQV);
                out[0] = (ws > 0.0f) ? (v / ws) : v;
            }
        }
    }
}

extern "C" void kernel_launch(void* const* d_in, const int* in_sizes, int n_in,
                              void* d_out, int out_size, void* d_ws, size_t ws_size,
                              hipStream_t stream)
{
    const float* pc   = (const float*)d_in[0];   // (1, N, 3)
    const float* flow = (const float*)d_in[1];   // (SEQ, N, 3)
    const float* wts  = (const float*)d_in[2];   // (N,)
    float* out = (float*)d_out;

    float*    accum  = (float*)d_ws;
    unsigned* hist   = (unsigned*)((char*)d_ws + WS_HIST);
    unsigned* starts = (unsigned*)((char*)d_ws + WS_STARTS);
    unsigned* sidx   = (unsigned*)((char*)d_ws + WS_SIDX);
    float4*   sorted = (float4*)  ((char*)d_ws + WS_SORTED);
    float4*   flowT  = (float4*)  ((char*)d_ws + WS_FLOWT);

    hist_kernel   <<<HBLK, 256, 0, stream>>>(pc, flow, hist, flowT);
    scatter_kernel<<<HBLK, 256, 0, stream>>>(pc, hist, starts, accum, sidx, sorted);
    mega_kernel   <<<NGRP, 1024, 0, stream>>>(sorted, sidx, starts, flowT, wts, accum, out);
}